// Round 6
// baseline (260.456 us; speedup 1.0000x reference)
//
#include <hip/hip_runtime.h>

typedef _Float16 half8 __attribute__((ext_vector_type(8)));
typedef _Float16 half4v __attribute__((ext_vector_type(4)));
typedef float floatx4 __attribute__((ext_vector_type(4)));

__device__ __forceinline__ floatx4 mfma16(half8 a, half8 b, floatx4 c) {
    return __builtin_amdgcn_mfma_f32_16x16x32_f16(a, b, c, 0, 0, 0);
}

// load 8 contiguous elements at element-offset off; optionally f32 source with
// in-register f32->f16 convert (identical rounding to the old cvt_all pass).
template<bool F32>
__device__ __forceinline__ half8 ldcvt8(const void* __restrict__ base, long off) {
    if constexpr (F32) {
        const float* p = (const float*)base + off;
        float4 a = *(const float4*)p;
        float4 b = *(const float4*)(p + 4);
        half8 h = {(_Float16)a.x, (_Float16)a.y, (_Float16)a.z, (_Float16)a.w,
                   (_Float16)b.x, (_Float16)b.y, (_Float16)b.z, (_Float16)b.w};
        return h;
    } else {
        return *(const half8*)((const _Float16*)base + off);
    }
}

// ---------------- TN GEMM, reg-staged pipeline, fused f32->f16 staging -------
// C[M,N] = A[M,K] * B[N,K]^T. 128x128 tile, BK=32, 256 threads, dbuf LDS.
// R11: cvt_all kernel DELETED — conversion fused into the reg-staged loads
// (reg-staging is why this variant is kept over gload_lds: a raw LDS-DMA
// can't convert).  AF32/BF32 select f32 sources (QKV: x, w_qkv; proj: w_proj).
// Structure = R0's best-measured 71-73us pipeline: global->VGPR right after
// barrier, compute from LDS, ds_write regs -> other buffer (vmcnt wait lands
// one compute phase after issue).  K=1024/grid-quantized shape plateaus at
// ~700 TF across all tried schedules (R1 gload_lds, R3 8-phase 256², R4
// 256x128 triple-buf) — keep best-measured.
// LDS swizzle: chunk c of row r -> slot c ^ ((r>>1)&3) (involution; verified
// SQ_LDS_BANK_CONFLICT = 0).  Epilogue: Cf -> f32+bias (proj); col>=split ->
// Vt transposed (QKV V: row>>10 = b, (col-split)>>6 = h); else Ch f16.
template<bool AF32, bool BF32>
__global__ __launch_bounds__(256, 4) void gemm_tn(
    const void* __restrict__ A, const void* __restrict__ B,
    _Float16* __restrict__ Ch, int ldc, _Float16* __restrict__ Vt, int split,
    float* __restrict__ Cf, const float* __restrict__ bias,
    int M, int Nn, int K)
{
    __shared__ _Float16 sA[2][128 * 32];
    __shared__ _Float16 sB[2][128 * 32];
    const int tid  = threadIdx.x;
    const int lane = tid & 63, wave = tid >> 6;
    const int quad = lane >> 4, l16 = lane & 15;
    const int wr = wave >> 1, wc = wave & 1;
    const long m0 = (long)blockIdx.x * 128, n0 = (long)blockIdx.y * 128;

    // thread tid owns row srow (and srow+64), 16B chunk (tid&3) of the 64B k-row.
    const int srow = tid >> 2;
    const int sslot = ((tid & 3) ^ ((srow >> 1) & 3)) * 8;
    const int dlo = srow * 32 + sslot;
    const int dhi = (srow + 64) * 32 + sslot;
    const long oA0 = (m0 + srow) * (long)K + (tid & 3) * 8;
    const long oA1 = (m0 + srow + 64) * (long)K + (tid & 3) * 8;
    const long oB0 = (n0 + srow) * (long)K + (tid & 3) * 8;
    const long oB1 = (n0 + srow + 64) * (long)K + (tid & 3) * 8;

    const int swz = (l16 >> 1) & 3;
    const int aoff = ((quad ^ swz) * 8);

    floatx4 acc[4][4] = {};
    const int nk = K >> 5;

    // prologue: tile 0 -> VGPR -> LDS buf 0
    half8 rA0 = ldcvt8<AF32>(A, oA0), rA1 = ldcvt8<AF32>(A, oA1);
    half8 rB0 = ldcvt8<BF32>(B, oB0), rB1 = ldcvt8<BF32>(B, oB1);
    *(half8*)&sA[0][dlo] = rA0; *(half8*)&sA[0][dhi] = rA1;
    *(half8*)&sB[0][dlo] = rB0; *(half8*)&sB[0][dhi] = rB1;

    for (int kk = 0; kk < nk; kk++) {
        const int cur = kk & 1;
        __syncthreads();               // lgkm drain only; vmcnt already 0 here
        const bool more = (kk + 1 < nk);
        if (more) {
            const long k0 = (long)(kk + 1) << 5;
            rA0 = ldcvt8<AF32>(A, oA0 + k0); rA1 = ldcvt8<AF32>(A, oA1 + k0);
            rB0 = ldcvt8<BF32>(B, oB0 + k0); rB1 = ldcvt8<BF32>(B, oB1 + k0);
        }

        const _Float16* cA = &sA[cur][0];
        const _Float16* cB = &sB[cur][0];
        half8 af[4], bf[4];
#pragma unroll
        for (int t = 0; t < 4; t++)
            af[t] = *(const half8*)&cA[(wr * 64 + t * 16 + l16) * 32 + aoff];
#pragma unroll
        for (int t = 0; t < 4; t++)
            bf[t] = *(const half8*)&cB[(wc * 64 + t * 16 + l16) * 32 + aoff];
#pragma unroll
        for (int tm = 0; tm < 4; tm++)
#pragma unroll
            for (int tn = 0; tn < 4; tn++)
                acc[tm][tn] = mfma16(af[tm], bf[tn], acc[tm][tn]);

        if (more) {
            _Float16* nA = &sA[cur ^ 1][0];
            _Float16* nB = &sB[cur ^ 1][0];
            *(half8*)&nA[dlo] = rA0; *(half8*)&nA[dhi] = rA1;   // vmcnt wait lands here,
            *(half8*)&nB[dlo] = rB0; *(half8*)&nB[dhi] = rB1;   // one compute phase after issue
        }
    }

    // epilogue: C/D layout col=lane&15, row=quad*4+reg (verified m89/m91)
#pragma unroll
    for (int tm = 0; tm < 4; tm++) {
        long row = m0 + wr * 64 + tm * 16 + quad * 4;
#pragma unroll
        for (int tn = 0; tn < 4; tn++) {
            long col = n0 + wc * 64 + tn * 16 + l16;
            if (Cf) {
                float bv = bias ? bias[col] : 0.f;
#pragma unroll
                for (int r = 0; r < 4; r++)
                    Cf[(row + r) * (long)Nn + col] = acc[tm][tn][r] + bv;
            } else if (col >= split) {
                // transposed V write: Vt[(b*16+h)*64+d][n], n = 4 consecutive rows
                long cv = col - split;
                long vrow = ((row >> 10) * 16 + (cv >> 6)) * 64 + (cv & 63);
                long nn = row & 1023;
                half4v pv = {(_Float16)acc[tm][tn][0], (_Float16)acc[tm][tn][1],
                             (_Float16)acc[tm][tn][2], (_Float16)acc[tm][tn][3]};
                *(half4v*)&Vt[vrow * 1024 + nn] = pv;
            } else {
#pragma unroll
                for (int r = 0; r < 4; r++)
                    Ch[(row + r) * (long)ldc + col] = (_Float16)acc[tm][tn][r];
            }
        }
    }
}

// ---------------- flash attention (S^T orientation) ----------------
// T14 async-STAGE split (K/V tile kt+1 global->reg issued right after tile
// kt's LDS stores; vmcnt wait lands at next iter's ds_write, one compute
// phase later) + T13 defer-max (skip O/l rescale while tile max growth <= 8;
// P bounded by e^8, f16-safe) + SCALE folded into Q at load (0.125 = 2^-3,
// exact in f16).
__global__ __launch_bounds__(256, 4) void flash_attn(const _Float16* __restrict__ qk,
                                                     const _Float16* __restrict__ vt,
                                                     _Float16* __restrict__ out)
{
    const int bh = blockIdx.x, b = bh >> 4, h = bh & 15;
    const int n0 = blockIdx.y * 128;
    const int tid = threadIdx.x, lane = tid & 63, wave = tid >> 6;
    const int quad = lane >> 4, l16 = lane & 15;

    __shared__ _Float16 sK[64 * 72];        // [kr][d] pad 72
    __shared__ _Float16 sVT[64 * 72];       // [d][kr] pad 72
    __shared__ _Float16 sPT[4][32 * 72];    // per-wave P^T round-trip [q][kr], reused as sOut

    half8 qf[2][2];
    const _Float16* qbase = qk + (long)(b * 1024 + n0 + wave * 32) * 2048 + h * 64;
#pragma unroll
    for (int t = 0; t < 2; t++)
#pragma unroll
        for (int s = 0; s < 2; s++) {
            half8 v = *(const half8*)(qbase + (long)(t * 16 + l16) * 2048 + s * 32 + quad * 8);
#pragma unroll
            for (int j = 0; j < 8; j++) v[j] *= (_Float16)0.125f;   // exact pow2
            qf[t][s] = v;
        }

    const int srow = tid >> 3, scol8 = (tid & 7) * 8;
    const _Float16* kgb = qk + 1024 + h * 64 + scol8 + (long)(b * 1024 + srow) * 2048;
    const _Float16* vgb = vt + (long)(bh * 64 + srow) * 1024 + scol8;

    float m_[2] = {-1e30f, -1e30f}, l_[2] = {0.f, 0.f};
    floatx4 o[2][4] = {};

    // T14 prologue: tile 0 -> regs
    half8 rK0 = *(const half8*)(kgb);
    half8 rK1 = *(const half8*)(kgb + (long)32 * 2048);
    half8 rV0 = *(const half8*)(vgb);
    half8 rV1 = *(const half8*)(vgb + (long)32 * 1024);

    for (int kt = 0; kt < 16; kt++) {
        __syncthreads();                       // prev tile's LDS readers done
        *(half8*)&sK[srow * 72 + scol8]          = rK0;
        *(half8*)&sK[(srow + 32) * 72 + scol8]   = rK1;
        *(half8*)&sVT[srow * 72 + scol8]         = rV0;
        *(half8*)&sVT[(srow + 32) * 72 + scol8]  = rV1;
        __syncthreads();

        if (kt + 1 < 16) {                     // issue kt+1 loads; waited at
            const long kr0n = (long)(kt + 1) * 64;          // next iter's stores
            rK0 = *(const half8*)(kgb + kr0n * 2048);
            rK1 = *(const half8*)(kgb + (kr0n + 32) * 2048);
            rV0 = *(const half8*)(vgb + kr0n);
            rV1 = *(const half8*)(vgb + (long)32 * 1024 + kr0n);
        }

        // S^T = K Q^T: A=K (m=kr), B=Q (n=q). C-layout: kr=c*16+quad*4+r, q=t*16+l16
        floatx4 sacc[2][4] = {};
#pragma unroll
        for (int c = 0; c < 4; c++)
#pragma unroll
            for (int s = 0; s < 2; s++) {
                half8 kf = *(const half8*)&sK[(c * 16 + l16) * 72 + s * 32 + quad * 8];
                sacc[0][c] = mfma16(kf, qf[0][s], sacc[0][c]);
                sacc[1][c] = mfma16(kf, qf[1][s], sacc[1][c]);
            }

        // online softmax over kr: in-lane reduce + 2 shuffles (xor16, xor32)
#pragma unroll
        for (int t = 0; t < 2; t++) {
            float mx = -1e30f;
#pragma unroll
            for (int c = 0; c < 4; c++)
#pragma unroll
                for (int r = 0; r < 4; r++)
                    mx = fmaxf(mx, sacc[t][c][r]);
            mx = fmaxf(mx, __shfl_xor(mx, 16));
            mx = fmaxf(mx, __shfl_xor(mx, 32));
            // T13 defer-max: only rescale when max grew past threshold
            if (__any(mx > m_[t] + 8.f)) {
                float mn = fmaxf(m_[t], mx);
                float al = __expf(m_[t] - mn);
                m_[t] = mn;
                l_[t] *= al;
#pragma unroll
                for (int dt = 0; dt < 4; dt++) o[t][dt] *= al;
            }
            float rs = 0.f;
#pragma unroll
            for (int c = 0; c < 4; c++)
#pragma unroll
                for (int r = 0; r < 4; r++) {
                    float p = __expf(sacc[t][c][r] - m_[t]);
                    sacc[t][c][r] = p;
                    rs += p;
                }
            rs += __shfl_xor(rs, 16);
            rs += __shfl_xor(rs, 32);
            l_[t] += rs;
            // pack P^T -> sPT[q][kr], one 8B half4 write per c-tile
#pragma unroll
            for (int c = 0; c < 4; c++) {
                half4v p = {(_Float16)sacc[t][c][0], (_Float16)sacc[t][c][1],
                            (_Float16)sacc[t][c][2], (_Float16)sacc[t][c][3]};
                *(half4v*)&sPT[wave][(t * 16 + l16) * 72 + c * 16 + quad * 4] = p;
            }
        }

        // PV: O^T += V^T P^T. A = V^T (m=d), B = P (n=q) from sPT.
#pragma unroll
        for (int kk = 0; kk < 2; kk++) {
            half8 pf0 = *(const half8*)&sPT[wave][(l16) * 72 + kk * 32 + quad * 8];
            half8 pf1 = *(const half8*)&sPT[wave][(16 + l16) * 72 + kk * 32 + quad * 8];
#pragma unroll
            for (int dt = 0; dt < 4; dt++) {
                half8 vf = *(const half8*)&sVT[(dt * 16 + l16) * 72 + kk * 32 + quad * 8];
                o[0][dt] = mfma16(vf, pf0, o[0][dt]);
                o[1][dt] = mfma16(vf, pf1, o[1][dt]);
            }
        }
    }

    // epilogue: normalize, per-wave LDS transpose (O^T -> O), coalesced 16B stores
#pragma unroll
    for (int t = 0; t < 2; t++) {
        float inv = 1.f / l_[t];
#pragma unroll
        for (int dt = 0; dt < 4; dt++) {
            floatx4 v = o[t][dt];
            half4v a = {(_Float16)(v[0] * inv), (_Float16)(v[1] * inv),
                        (_Float16)(v[2] * inv), (_Float16)(v[3] * inv)};
            *(half4v*)&sPT[wave][(t * 16 + l16) * 72 + dt * 16 + quad * 4] = a;
        }
    }
    __syncthreads();
#pragma unroll
    for (int i = 0; i < 4; i++) {
        int ql = i * 8 + (lane >> 3);
        int c8 = (lane & 7) * 8;
        half8 vv = *(const half8*)&sPT[wave][ql * 72 + c8];
        *(half8*)(out + (long)(b * 1024 + n0 + wave * 32 + ql) * 1024 + h * 64 + c8) = vv;
    }
}

// ---------------- launch ----------------
extern "C" void kernel_launch(void* const* d_in, const int* in_sizes, int n_in,
                              void* d_out, int out_size, void* d_ws, size_t ws_size,
                              hipStream_t stream) {
    const float* x      = (const float*)d_in[0];
    const float* w_qkv  = (const float*)d_in[1];
    const float* w_proj = (const float*)d_in[2];
    const float* b_proj = (const float*)d_in[3];

    char* ws = (char*)d_ws;
    _Float16* qkh   = (_Float16*)ws;                      // 32MB [8192][2048] (Q|K)
    _Float16* vT    = (_Float16*)(ws + 33554432);         // 16MB [128*64][1024] (V^T)
    _Float16* attnh = (_Float16*)(ws + 50331648);         // 16MB [8192][1024] flash out

    // QKV GEMM, conversion fused (A=x f32, B=w_qkv f32):
    // cols 0..2047 -> qkh row-major, cols 2048..3071 -> vT transposed
    gemm_tn<true, true><<<dim3(64, 24), 256, 0, stream>>>(
        x, w_qkv, qkh, 2048, vT, 2048, nullptr, nullptr, 8192, 3072, 1024);
    flash_attn<<<dim3(128, 8), 256, 0, stream>>>(qkh, vT, attnh);
    // proj GEMM (A=attnh f16, B=w_proj f32 fused-converted): f32 + bias epilogue
    gemm_tn<false, true><<<dim3(64, 8), 256, 0, stream>>>(
        attnh, w_proj, nullptr, 0, nullptr, 1 << 30,
        (float*)d_out, b_proj, 8192, 1024, 1024);
}